// Round 1
// baseline (397.230 us; speedup 1.0000x reference)
//
#include <hip/hip_runtime.h>
#include <cstdint>

namespace {
constexpr int B = 8, C = 3, H = 1024, W = 1024;
constexpr int HO = 256, WO = 256, K2 = 9;
constexpr int HP = H + 2, WP = W + 2;

__device__ __forceinline__ int reflect_src(int p, int n) {
    // padded index p in [0, n+1] -> source index in [0, n-1]
    // source = p-1; reflect (numpy 'reflect', no edge repeat): -1 -> 1, n -> n-2
    int s = p - 1;
    s = (s < 0) ? -s : s;
    s = (s >= n) ? (2 * n - 2 - s) : s;
    return s;
}

__global__ __launch_bounds__(256) void ds_kernel(
    const float* __restrict__ img,
    const float* __restrict__ kern,
    const float* __restrict__ offh,
    const float* __restrict__ offv,
    const float* __restrict__ ou_p,
    float* __restrict__ out) {
    int idx = blockIdx.x * blockDim.x + threadIdx.x;
    int w = idx & (WO - 1);
    int h = (idx >> 8) & (HO - 1);
    int b = idx >> 16;
    if (b >= B) return;

    const float ou = ou_p[0];
    const float cy = (h + 0.5f) * 4.0f - 0.5f;
    const float cx = (w + 0.5f) * 4.0f - 0.5f;
    const float* img0 = img + (size_t)b * (C * H * W);
    const float* img1 = img0 + H * W;
    const float* img2 = img1 + H * W;

    float acc0 = 0.f, acc1 = 0.f, acc2 = 0.f;
    size_t pbase = ((size_t)b * K2) * (size_t)(HO * WO) + (size_t)h * WO + w;

#pragma unroll
    for (int k = 0; k < K2; ++k) {
        size_t o = pbase + (size_t)(k * HO * WO);
        float kv = kern[o];
        float py = cy + (float)(k / 3) + offv[o] * ou;
        float px = cx + (float)(k % 3) + offh[o] * ou;

        float y0f = floorf(py), x0f = floorf(px);
        float bb = py - y0f;   // beta  (from unclamped floor)
        float aa = px - x0f;   // alpha (from unclamped floor)

        int y0 = (int)y0f, x0 = (int)x0f;
        y0 = min(max(y0, 0), HP - 1);
        x0 = min(max(x0, 0), WP - 1);
        int y1 = min(y0 + 1, HP - 1);   // note: clamp of (clamped y0)+1, per reference
        int x1 = min(x0 + 1, WP - 1);

        int sy0 = reflect_src(y0, H), sy1 = reflect_src(y1, H);
        int sx0 = reflect_src(x0, W), sx1 = reflect_src(x1, W);

        float w00 = (1.f - aa) * (1.f - bb);
        float w01 = aa * (1.f - bb);
        float w10 = (1.f - aa) * bb;
        float w11 = aa * bb;

        int i00 = sy0 * W + sx0;
        int i01 = sy0 * W + sx1;
        int i10 = sy1 * W + sx0;
        int i11 = sy1 * W + sx1;

        acc0 += kv * (w00 * img0[i00] + w01 * img0[i01] + w10 * img0[i10] + w11 * img0[i11]);
        acc1 += kv * (w00 * img1[i00] + w01 * img1[i01] + w10 * img1[i10] + w11 * img1[i11]);
        acc2 += kv * (w00 * img2[i00] + w01 * img2[i01] + w10 * img2[i10] + w11 * img2[i11]);
    }

    size_t obase = ((size_t)b * C) * (size_t)(HO * WO) + (size_t)h * WO + w;
    out[obase] = acc0;
    out[obase + (size_t)(HO * WO)] = acc1;
    out[obase + (size_t)(2 * HO * WO)] = acc2;
}
} // namespace

extern "C" void kernel_launch(void* const* d_in, const int* in_sizes, int n_in,
                              void* d_out, int out_size, void* d_ws, size_t ws_size,
                              hipStream_t stream) {
    const float* img  = (const float*)d_in[0];
    const float* kern = (const float*)d_in[1];
    const float* offh = (const float*)d_in[2];
    const float* offv = (const float*)d_in[3];
    const float* ou   = (const float*)d_in[4];
    float* out = (float*)d_out;

    int total = B * HO * WO;           // 524288 threads, one per (b, h_out, w_out)
    dim3 block(256);
    dim3 grid((total + 255) / 256);
    hipLaunchKernelGGL(ds_kernel, grid, block, 0, stream,
                       img, kern, offh, offv, ou, out);
}